// Round 4
// baseline (209.855 us; speedup 1.0000x reference)
//
#include <hip/hip_runtime.h>

#define BATCH 32768
#define SEQLEN 12
#define NBLK 2048   // one 64-lane wave per block, 16 peds (2 scenes)

typedef short short8 __attribute__((ext_vector_type(8)));
typedef float f32x4 __attribute__((ext_vector_type(4)));
typedef unsigned short ushort_t;

static __device__ __forceinline__ unsigned short f2bf(float x) {
    unsigned u = __float_as_uint(x);
    return (unsigned short)((u + 0x7FFFu + ((u >> 16) & 1u)) >> 16);  // RNE
}
static __device__ __forceinline__ float bf2f(unsigned short h) {
    return __uint_as_float(((unsigned)h) << 16);
}

#define MFMA __builtin_amdgcn_mfma_f32_16x16x32_bf16

// ---------------- wave-private phase macros ----------------
// s1 staging: one column [ped][ic] (padded 72), scatter-written by lane=ic,
// frag-read by lane (kg,n). Same-wave DS is FIFO; __syncthreads in a 64-thread
// block is ~free and fences compiler reordering.
#define S1_FRAGREAD(SL) do {                                                  \
    __syncthreads();                                                          \
    s1fh[SL][0] = *(const short8*)&s1sh[n][kg*8];                             \
    s1fh[SL][1] = *(const short8*)&s1sh[n][32 + kg*8];                        \
    s1fl[SL][0] = *(const short8*)&s1sl[n][kg*8];                             \
    s1fl[SL][1] = *(const short8*)&s1sl[n][32 + kg*8];                        \
} while(0)

// warm-up conv1 column c (all 3 taps from pos ring), exact fp32, same op order
// as the verified kernel.
#define WCONV1(c_) do {                                                       \
    _Pragma("unroll")                                                         \
    for (int p = 0; p < 16; ++p) {                                            \
        float2 pa = *(const float2*)&pos_s[(c_)    ][p][0];                   \
        float2 pb = *(const float2*)&pos_s[(c_) + 1][p][0];                   \
        float2 pc = *(const float2*)&pos_s[(c_) + 2][p][0];                   \
        float v = cK1;                                                        \
        v = fmaf(ccA0, pa.x, v); v = fmaf(ccB0, pa.y, v);                     \
        v = fmaf(ccA1, pb.x, v); v = fmaf(ccB1, pb.y, v);                     \
        v = fmaf(ccA2, pc.x, v); v = fmaf(ccB2, pc.y, v);                     \
        v = fmaxf(v, 0.f);                                                    \
        ushort_t h = f2bf(v);                                                 \
        s1sh[p][lane] = h; s1sl[p][lane] = f2bf(v - bf2f(h));                 \
    }                                                                         \
    S1_FRAGREAD((c_) % 3);                                                    \
} while(0)

// conv2 column with col%3 == CM3: reads s1 frag slots (CM3+tap)%3, writes the
// s2 1-col staging, reloads s2 frag slot CM3. Numerics identical to verified.
#define CONV2W(CM3) do {                                                      \
    _Pragma("unroll")                                                         \
    for (int T = 0; T < 2; ++T) {                                             \
        f32x4 a1 = {0.f,0.f,0.f,0.f}, a2 = {0.f,0.f,0.f,0.f},                 \
              a3 = {0.f,0.f,0.f,0.f};                                         \
        _Pragma("unroll")                                                     \
        for (int kb = 0; kb < 6; ++kb) {                                      \
            const int sl = ((CM3) + (kb >> 1)) % 3, ich = kb & 1;             \
            a1 = MFMA(c2h[T][kb], s1fh[sl][ich], a1, 0, 0, 0);                \
            a2 = MFMA(c2h[T][kb], s1fl[sl][ich], a2, 0, 0, 0);                \
            a3 = MFMA(c2l[T][kb], s1fh[sl][ich], a3, 0, 0, 0);                \
        }                                                                     \
        float w0 = fmaxf(a1[0]+a2[0]+a3[0]+b2r[T][0], 0.f);                   \
        float w1 = fmaxf(a1[1]+a2[1]+a3[1]+b2r[T][1], 0.f);                   \
        float w2 = fmaxf(a1[2]+a2[2]+a3[2]+b2r[T][2], 0.f);                   \
        float w3 = fmaxf(a1[3]+a2[3]+a3[3]+b2r[T][3], 0.f);                   \
        ushort_t h0=f2bf(w0), h1=f2bf(w1), h2=f2bf(w2), h3=f2bf(w3);          \
        *(uint2*)&s2sh[n][T*16 + kg*4] = make_uint2(                          \
            (unsigned)h0 | ((unsigned)h1 << 16),                              \
            (unsigned)h2 | ((unsigned)h3 << 16));                             \
        *(uint2*)&s2sl[n][T*16 + kg*4] = make_uint2(                          \
            (unsigned)f2bf(w0-bf2f(h0)) | ((unsigned)f2bf(w1-bf2f(h1)) << 16),\
            (unsigned)f2bf(w2-bf2f(h2)) | ((unsigned)f2bf(w3-bf2f(h3)) << 16));\
    }                                                                         \
    __syncthreads();                                                          \
    s2fh[(CM3)] = *(const short8*)&s2sh[n][kg*8];                             \
    s2fl[(CM3)] = *(const short8*)&s2sl[n][kg*8];                             \
} while(0)

// conv3 column (col%3 == CM3, col&1 == PARI): outputs + scene-max stay in regs.
#define CONV3W(CM3, PARI) do {                                                \
    _Pragma("unroll")                                                         \
    for (int T = 0; T < 2; ++T) {                                             \
        f32x4 a1 = {0.f,0.f,0.f,0.f}, a2 = {0.f,0.f,0.f,0.f},                 \
              a3 = {0.f,0.f,0.f,0.f};                                         \
        _Pragma("unroll")                                                     \
        for (int kb = 0; kb < 3; ++kb) {                                      \
            const int sl = ((CM3) + kb) % 3;                                  \
            a1 = MFMA(c3h[T][kb], s2fh[sl], a1, 0, 0, 0);                     \
            a2 = MFMA(c3h[T][kb], s2fl[sl], a2, 0, 0, 0);                     \
            a3 = MFMA(c3l[T][kb], s2fh[sl], a3, 0, 0, 0);                     \
        }                                                                     \
        float m0 = fmaxf(a1[0]+a2[0]+a3[0]+b3r[T][0], 0.f);                   \
        float m1 = fmaxf(a1[1]+a2[1]+a3[1]+b3r[T][1], 0.f);                   \
        float m2 = fmaxf(a1[2]+a2[2]+a3[2]+b3r[T][2], 0.f);                   \
        float m3 = fmaxf(a1[3]+a2[3]+a3[3]+b3r[T][3], 0.f);                   \
        c3c[PARI][T] = (f32x4){m0, m1, m2, m3};                               \
        _Pragma("unroll")                                                     \
        for (int msk = 1; msk <= 4; msk <<= 1) {                              \
            m0 = fmaxf(m0, __shfl_xor(m0, msk));                              \
            m1 = fmaxf(m1, __shfl_xor(m1, msk));                              \
            m2 = fmaxf(m2, __shfl_xor(m2, msk));                              \
            m3 = fmaxf(m3, __shfl_xor(m3, msk));                              \
        }                                                                     \
        mxc[PARI][T] = (f32x4){m0, m1, m2, m3};                               \
    }                                                                         \
} while(0)

// one recurrent step: h2p(st) -> conv1 col st+6 -> conv2 col st+4 -> conv3 col st+2
#define STEP(K) do {                                                          \
    const int st = sbase + (K);                                               \
    const bool more = (st < SEQLEN-1);                                        \
    float base16[16];                                                         \
    if (more) {                                                               \
        const float* pA = &pos_s[(st+6) & 7][0][0];                           \
        const float* pB = &pos_s[(st+7) & 7][0][0];                           \
        _Pragma("unroll")                                                     \
        for (int p = 0; p < 16; ++p) {                                        \
            float v = cK1;                                                    \
            v = fmaf(ccA0, pA[p*2], v); v = fmaf(ccB0, pA[p*2+1], v);         \
            v = fmaf(ccA1, pB[p*2], v); v = fmaf(ccB1, pB[p*2+1], v);         \
            base16[p] = v;                                                    \
        }                                                                     \
    }                                                                         \
    float pv0a = 0.f, pv0b = 0.f, pv1a = 0.f, pv1b = 0.f;                     \
    {                                                                         \
        const float4* wq = (const float4*)&whp_s[kg][0];                      \
        _Pragma("unroll")                                                     \
        for (int q = 0; q < 16; ++q) {                                        \
            float4 ww = wq[q];                                                \
            _Pragma("unroll")                                                 \
            for (int e = 0; e < 4; ++e) {                                     \
                const int j2 = (q & 7)*4 + e;                                 \
                const int jj = j2 & 15;                                       \
                const int T = jj >> 3, r = (jj >> 1) & 3, col = jj & 1;       \
                const int par = col ? ((K+1) & 1) : ((K) & 1);                \
                float val = (j2 < 16) ? c3c[par][T][r] : mxc[par][T][r];      \
                float wv_ = (e==0)?ww.x:(e==1)?ww.y:(e==2)?ww.z:ww.w;         \
                if (q < 8) { if (q & 1) pv0b = fmaf(wv_, val, pv0b);          \
                             else       pv0a = fmaf(wv_, val, pv0a); }        \
                else       { if (q & 1) pv1b = fmaf(wv_, val, pv1b);          \
                             else       pv1a = fmaf(wv_, val, pv1a); }        \
            }                                                                 \
        }                                                                     \
    }                                                                         \
    float pv0 = pv0a + pv0b, pv1 = pv1a + pv1b;                               \
    pv0 += __shfl_xor(pv0, 16); pv0 += __shfl_xor(pv0, 32);                   \
    pv1 += __shfl_xor(pv1, 16); pv1 += __shfl_xor(pv1, 32);                   \
    const float r0 = pv0 + bhp0, r1 = pv1 + bhp1;                             \
    if (lane < 16) {                                                          \
        float2 o; o.x = r0; o.y = r1;                                         \
        *(float2*)&out[(size_t)(st*BATCH + bped + lane)*2] = o;               \
    }                                                                         \
    if (more) {                                                               \
        if (lane < 16) { float2 o2; o2.x = r0; o2.y = r1;                     \
            *(float2*)&pos_s[st & 7][lane][0] = o2; }                         \
        float r0g[16], r1g[16];                                               \
        _Pragma("unroll")                                                     \
        for (int p = 0; p < 16; ++p) {                                        \
            r0g[p] = __shfl(r0, p); r1g[p] = __shfl(r1, p);                   \
        }                                                                     \
        _Pragma("unroll")                                                     \
        for (int p = 0; p < 16; ++p) {                                        \
            float v = fmaf(ccB2, r1g[p], fmaf(ccA2, r0g[p], base16[p]));      \
            v = fmaxf(v, 0.f);                                                \
            ushort_t h = f2bf(v);                                             \
            s1sh[p][lane] = h; s1sl[p][lane] = f2bf(v - bf2f(h));             \
        }                                                                     \
        S1_FRAGREAD((K) % 3);            /* col st+6 -> slot (st+6)%3 = K%3 */\
        CONV2W((K+1) % 3);               /* col st+4 */                       \
        CONV3W((K+2) % 3, (K) & 1);      /* col st+2, parity st&1 */          \
    }                                                                         \
} while(0)

__global__ __launch_bounds__(64, 1)
void enc_wave(const float* __restrict__ obs,
              const float* __restrict__ Wse, const float* __restrict__ bse,
              const float* __restrict__ v1, const float* __restrict__ g1, const float* __restrict__ b1,
              const float* __restrict__ v2, const float* __restrict__ g2, const float* __restrict__ b2,
              const float* __restrict__ v3, const float* __restrict__ g3, const float* __restrict__ b3,
              const float* __restrict__ Whp, const float* __restrict__ bhp,
              float* __restrict__ out)
{
    __shared__ __align__(16) ushort_t s1sh[16][72], s1sl[16][72];  // 1-col stage, padded
    __shared__ __align__(16) ushort_t s2sh[16][40], s2sl[16][40];
    __shared__ __align__(16) float pos_s[8][16][2];
    __shared__ __align__(16) float whp_s[4][64];                   // Whp, frag-sliced per kg
    __shared__ __align__(16) float wse_s[128], bse_s[64], sc2_s[32], sc3_s[32];

    const int lane = threadIdx.x;
    const int n = lane & 15, kg = lane >> 4;
    const int bped = blockIdx.x * 16;

    // ---- stage small tensors ----
    wse_s[lane] = Wse[lane]; wse_s[64 + lane] = Wse[64 + lane];
    bse_s[lane] = bse[lane];
    #pragma unroll
    for (int q = 0; q < 4; ++q) {        // Whp -> per-kg h2p slices
        int d = lane >> 5, jp = lane & 31, jj = jp & 15;
        int T = jj >> 3, r = (jj >> 1) & 3, col = jj & 1;
        int off = (T*16 + q*4 + r)*2 + col + ((jp >= 16) ? 64 : 0);
        whp_s[q][lane] = Whp[d*128 + off];
    }
    #pragma unroll
    for (int q = 0; q < 4; ++q) {        // obs window
        int flat = q*64 + lane;
        int tau = flat >> 5, p = (flat >> 1) & 15, c = flat & 1;
        pos_s[tau][p][c] = obs[(size_t)(tau*BATCH + bped + p)*2 + c];
    }

    // ---- weight-norm scales ----
    float sc1;
    {
        const float* v = v1 + lane*192; float s = 0.f;
        for (int j = 0; j < 192; ++j) s += v[j]*v[j];
        sc1 = g1[lane] / sqrtf(s);
    }
    if (lane < 32) {
        const float* v = v2 + lane*192; float s = 0.f;
        for (int j = 0; j < 192; ++j) s += v[j]*v[j];
        sc2_s[lane] = g2[lane] / sqrtf(s);
    } else {
        const float* v = v3 + (lane-32)*96; float s = 0.f;
        for (int j = 0; j < 96; ++j) s += v[j]*v[j];
        sc3_s[lane-32] = g3[lane-32] / sqrtf(s);
    }
    __syncthreads();

    // ---- conv1 collapse coefficients (lane = oc), exact fp32, same op order ----
    float ccA0, ccA1, ccA2, ccB0, ccB1, ccB2, cK1;
    {
        float dA0=0,dA1=0,dA2=0,dB0=0,dB1=0,dB2=0,dC0=0,dC1=0,dC2=0;
        const float* vr = v1 + lane*192;
        #pragma unroll 4
        for (int ic = 0; ic < 64; ++ic) {
            float w0 = vr[ic*3], w1 = vr[ic*3+1], w2 = vr[ic*3+2];
            float we0 = wse_s[ic*2], we1 = wse_s[ic*2+1], be = bse_s[ic];
            dA0 = fmaf(w0, we0, dA0); dB0 = fmaf(w0, we1, dB0); dC0 = fmaf(w0, be, dC0);
            dA1 = fmaf(w1, we0, dA1); dB1 = fmaf(w1, we1, dB1); dC1 = fmaf(w1, be, dC1);
            dA2 = fmaf(w2, we0, dA2); dB2 = fmaf(w2, we1, dB2); dC2 = fmaf(w2, be, dC2);
        }
        ccA0 = sc1*dA0; ccA1 = sc1*dA1; ccA2 = sc1*dA2;
        ccB0 = sc1*dB0; ccB1 = sc1*dB1; ccB2 = sc1*dB2;
        float cs = (dC0 + dC1) + dC2;
        cK1 = fmaf(sc1, cs, b1[lane]);
    }

    // ---- persistent MFMA A-fragments (both oc-tiles per wave) ----
    short8 c2h[2][6], c2l[2][6], c3h[2][3], c3l[2][3];
    float b2r[2][4], b3r[2][4];
    #pragma unroll
    for (int T = 0; T < 2; ++T) {
        const int oc2 = T*16 + n;
        const float s2s = sc2_s[oc2];
        #pragma unroll
        for (int kb = 0; kb < 6; ++kb) {
            const int tap = kb >> 1, ich = kb & 1;
            #pragma unroll
            for (int j = 0; j < 8; ++j) {
                const int ic = ich*32 + kg*8 + j;
                float w = v2[(size_t)(oc2*64 + ic)*3 + tap] * s2s;
                ushort_t hb = f2bf(w);
                c2h[T][kb][j] = (short)hb;
                c2l[T][kb][j] = (short)f2bf(w - bf2f(hb));
            }
        }
        const float s3s = sc3_s[oc2];
        #pragma unroll
        for (int kb = 0; kb < 3; ++kb) {
            #pragma unroll
            for (int j = 0; j < 8; ++j) {
                const int ic = kg*8 + j;
                float w = v3[(size_t)(oc2*32 + ic)*3 + kb] * s3s;
                ushort_t hb = f2bf(w);
                c3h[T][kb][j] = (short)hb;
                c3l[T][kb][j] = (short)f2bf(w - bf2f(hb));
            }
        }
        #pragma unroll
        for (int r = 0; r < 4; ++r) {
            b2r[T][r] = b2[T*16 + kg*4 + r];
            b3r[T][r] = b3[T*16 + kg*4 + r];
        }
    }
    const float bhp0 = bhp[0], bhp1 = bhp[1];

    // ---- rotating activation state ----
    short8 s1fh[3][2], s1fl[3][2], s2fh[3], s2fl[3];
    f32x4 c3c[2][2], mxc[2][2];

    // ---- warm-up (cols 0..5 / conv2 0..3 / conv3 0..1), slot = col%3 ----
    WCONV1(0); WCONV1(1); WCONV1(2);
    CONV2W(0);          // conv2 col 0 (s1 cols 0,1,2) -> s2 slot 0
    WCONV1(3);          // s1 slot 0 <- col 3
    CONV2W(1);          // col 1 (1,2,3) -> s2 slot 1
    WCONV1(4);          // s1 slot 1 <- col 4
    CONV2W(2);          // col 2 (2,3,4) -> s2 slot 2
    WCONV1(5);          // s1 slot 2 <- col 5
    CONV3W(0, 0);       // conv3 col 0 (s2 cols 0,1,2) -> parity 0
    CONV2W(0);          // conv2 col 3 (3,4,5) -> s2 slot 0 (col 0 now dead)
    CONV3W(1, 1);       // conv3 col 1 (1,2,3) -> parity 1

    // ---- 12 recurrent steps, zero inter-wave sync ----
    for (int hh = 0; hh < 2; ++hh) {
        const int sbase = hh * 6;
        STEP(0); STEP(1); STEP(2); STEP(3); STEP(4); STEP(5);
    }
}

extern "C" void kernel_launch(void* const* d_in, const int* in_sizes, int n_in,
                              void* d_out, int out_size, void* d_ws, size_t ws_size,
                              hipStream_t stream)
{
    const float* obs = (const float*)d_in[0];
    // d_in[1] last_pos, d_in[2] last_pos_rel: dead state (never reaches output)
    const float* Wse = (const float*)d_in[3];
    const float* bse = (const float*)d_in[4];
    const float* v1  = (const float*)d_in[5];
    const float* g1  = (const float*)d_in[6];
    const float* b1  = (const float*)d_in[7];
    const float* v2  = (const float*)d_in[8];
    const float* g2  = (const float*)d_in[9];
    const float* b2  = (const float*)d_in[10];
    const float* v3  = (const float*)d_in[11];
    const float* g3  = (const float*)d_in[12];
    const float* b3  = (const float*)d_in[13];
    const float* Whp = (const float*)d_in[14];
    const float* bhp = (const float*)d_in[15];
    // d_in[16] seq_start_end: structurally seg = ped>>3 ; d_in[17] seq_len = 12

    enc_wave<<<NBLK, 64, 0, stream>>>(obs, Wse, bse, v1, g1, b1, v2, g2, b2,
                                      v3, g3, b3, Whp, bhp, (float*)d_out);
}

// Round 5
// 206.916 us; speedup vs baseline: 1.0142x; 1.0142x over previous
//
#include <hip/hip_runtime.h>

#define BATCH 32768
#define SEQLEN 12
#define NBLK 512   // 256 threads = 4 waves; each wave privately owns 16 peds (2 scenes)

typedef short short8 __attribute__((ext_vector_type(8)));
typedef float f32x4 __attribute__((ext_vector_type(4)));
typedef unsigned short ushort_t;

static __device__ __forceinline__ unsigned short f2bf(float x) {
    unsigned u = __float_as_uint(x);
    return (unsigned short)((u + 0x7FFFu + ((u >> 16) & 1u)) >> 16);  // RNE
}
static __device__ __forceinline__ float bf2f(unsigned short h) {
    return __uint_as_float(((unsigned)h) << 16);
}

#define MFMA __builtin_amdgcn_mfma_f32_16x16x32_bf16

// Wave-private v2: every conv1->conv2->conv3->h2p hop is same-wave, so no
// __syncthreads in the main loop (per-wave DS is in-order; compiler orders
// LDS RAW). Register diet vs r4 (which overflowed the unified VGPR+AGPR
// file past 256 -> 1 wave/SIMD): conv3 weights + biases shared in LDS,
// s2 ring in LDS, no base16/bpermute-broadcast. Target combined <=256 ->
// 2 waves/SIMD; 512 blocks = 2 blocks/CU, all resident.

// ---- conv1: one ped column element (exact fp32, same op order as verified) ----
#define C1PED(PX, PY, QX, QY, RX, RY, PPED) do {                              \
    float v_ = cK1;                                                           \
    v_ = fmaf(ccA0, PX, v_); v_ = fmaf(ccB0, PY, v_);                         \
    v_ = fmaf(ccA1, QX, v_); v_ = fmaf(ccB1, QY, v_);                         \
    v_ = fmaf(ccA2, RX, v_); v_ = fmaf(ccB2, RY, v_);                         \
    v_ = fmaxf(v_, 0.f);                                                      \
    ushort_t h_ = f2bf(v_);                                                   \
    s1sh[wv][PPED][lane] = h_;                                                \
    s1sl[wv][PPED][lane] = f2bf(v_ - bf2f(h_));                               \
} while(0)

#define S1_FRAGREAD(SL) do {                                                  \
    s1fh[SL][0] = *(const short8*)&s1sh[wv][n][kg*8];                         \
    s1fh[SL][1] = *(const short8*)&s1sh[wv][n][32 + kg*8];                    \
    s1fl[SL][0] = *(const short8*)&s1sl[wv][n][kg*8];                         \
    s1fl[SL][1] = *(const short8*)&s1sl[wv][n][32 + kg*8];                    \
} while(0)

// conv1 column from pos ring slots SA,SB,SC -> s1 staging -> reg frag slot SL
#define CONV1COL(SA, SB, SC, SL) do {                                         \
    _Pragma("unroll")                                                         \
    for (int pp_ = 0; pp_ < 8; ++pp_) {                                       \
        float4 fa_ = *(const float4*)&pos_s[wv][SA][2*pp_][0];                \
        float4 fb_ = *(const float4*)&pos_s[wv][SB][2*pp_][0];                \
        float4 fc_ = *(const float4*)&pos_s[wv][SC][2*pp_][0];                \
        C1PED(fa_.x, fa_.y, fb_.x, fb_.y, fc_.x, fc_.y, 2*pp_);               \
        C1PED(fa_.z, fa_.w, fb_.z, fb_.w, fc_.z, fc_.w, 2*pp_+1);             \
    }                                                                         \
    S1_FRAGREAD(SL);                                                          \
} while(0)

// conv2 column c (c%3 == CM3): s1 reg frags -> s2 LDS ring slot CM3
#define CONV2COL(CM3) do {                                                    \
    _Pragma("unroll")                                                         \
    for (int T = 0; T < 2; ++T) {                                             \
        f32x4 a1 = {0.f,0.f,0.f,0.f}, a2 = {0.f,0.f,0.f,0.f},                 \
              a3 = {0.f,0.f,0.f,0.f};                                         \
        _Pragma("unroll")                                                     \
        for (int kb = 0; kb < 6; ++kb) {                                      \
            const int sl = ((CM3) + (kb >> 1)) % 3, ich = kb & 1;             \
            a1 = MFMA(c2h[T][kb], s1fh[sl][ich], a1, 0, 0, 0);                \
            a2 = MFMA(c2h[T][kb], s1fl[sl][ich], a2, 0, 0, 0);                \
            a3 = MFMA(c2l[T][kb], s1fh[sl][ich], a3, 0, 0, 0);                \
        }                                                                     \
        const float4 bb = *(const float4*)&b2s[T*16 + kg*4];                  \
        float w0 = fmaxf(a1[0]+a2[0]+a3[0]+bb.x, 0.f);                        \
        float w1 = fmaxf(a1[1]+a2[1]+a3[1]+bb.y, 0.f);                        \
        float w2 = fmaxf(a1[2]+a2[2]+a3[2]+bb.z, 0.f);                        \
        float w3 = fmaxf(a1[3]+a2[3]+a3[3]+bb.w, 0.f);                        \
        ushort_t h0=f2bf(w0), h1=f2bf(w1), h2=f2bf(w2), h3=f2bf(w3);          \
        *(uint2*)&s2sh[wv][CM3][n][T*16 + kg*4] = make_uint2(                 \
            (unsigned)h0 | ((unsigned)h1 << 16),                              \
            (unsigned)h2 | ((unsigned)h3 << 16));                             \
        *(uint2*)&s2sl[wv][CM3][n][T*16 + kg*4] = make_uint2(                 \
            (unsigned)f2bf(w0-bf2f(h0)) | ((unsigned)f2bf(w1-bf2f(h1)) << 16),\
            (unsigned)f2bf(w2-bf2f(h2)) | ((unsigned)f2bf(w3-bf2f(h3)) << 16));\
    }                                                                         \
} while(0)

// conv3 column v (v%3 == VM3, v&1 == PARI): s2 LDS ring + shared LDS weights
#define CONV3COL(VM3, PARI) do {                                              \
    short8 sbh_[3], sbl_[3];                                                  \
    _Pragma("unroll")                                                         \
    for (int kb = 0; kb < 3; ++kb) {                                          \
        const int sl = ((VM3) + kb) % 3;                                      \
        sbh_[kb] = *(const short8*)&s2sh[wv][sl][n][kg*8];                    \
        sbl_[kb] = *(const short8*)&s2sl[wv][sl][n][kg*8];                    \
    }                                                                         \
    _Pragma("unroll")                                                         \
    for (int T = 0; T < 2; ++T) {                                             \
        f32x4 a1 = {0.f,0.f,0.f,0.f}, a2 = {0.f,0.f,0.f,0.f},                 \
              a3 = {0.f,0.f,0.f,0.f};                                         \
        _Pragma("unroll")                                                     \
        for (int kb = 0; kb < 3; ++kb) {                                      \
            const short8 wh = *(const short8*)&c3wh[T*3+kb][lane][0];         \
            const short8 wl = *(const short8*)&c3wl[T*3+kb][lane][0];         \
            a1 = MFMA(wh, sbh_[kb], a1, 0, 0, 0);                             \
            a2 = MFMA(wh, sbl_[kb], a2, 0, 0, 0);                             \
            a3 = MFMA(wl, sbh_[kb], a3, 0, 0, 0);                             \
        }                                                                     \
        const float4 b3v = *(const float4*)&b3s[T*16 + kg*4];                 \
        float m0 = fmaxf(a1[0]+a2[0]+a3[0]+b3v.x, 0.f);                       \
        float m1 = fmaxf(a1[1]+a2[1]+a3[1]+b3v.y, 0.f);                       \
        float m2 = fmaxf(a1[2]+a2[2]+a3[2]+b3v.z, 0.f);                       \
        float m3 = fmaxf(a1[3]+a2[3]+a3[3]+b3v.w, 0.f);                       \
        c3c[PARI][T] = (f32x4){m0, m1, m2, m3};                               \
        _Pragma("unroll")                                                     \
        for (int msk = 1; msk <= 4; msk <<= 1) {                              \
            m0 = fmaxf(m0, __shfl_xor(m0, msk));                              \
            m1 = fmaxf(m1, __shfl_xor(m1, msk));                              \
            m2 = fmaxf(m2, __shfl_xor(m2, msk));                              \
            m3 = fmaxf(m3, __shfl_xor(m3, msk));                              \
        }                                                                     \
        mxc[PARI][T] = (f32x4){m0, m1, m2, m3};                               \
    }                                                                         \
} while(0)

// stage obs taus T0,T0+1 into pos ring (slot = tau&3)
#define STAGE2(T0) do {                                                       \
    const int tau_ = (T0) + (lane >> 5);                                      \
    const int p_ = (lane >> 1) & 15, c_ = lane & 1;                           \
    pos_s[wv][tau_ & 3][p_][c_] =                                             \
        obs[(size_t)(tau_*BATCH + bped + p_)*2 + c_];                         \
} while(0)

// one recurrent step: h2p(st) -> conv1(st+6) -> conv2(st+4) -> conv3(st+2)
#define STEP(K) do {                                                          \
    const int st = sbase + (K);                                               \
    float pv0a = 0.f, pv0b = 0.f, pv1a = 0.f, pv1b = 0.f;                     \
    {                                                                         \
        const float4* wq = (const float4*)&whp_s[kg][0];                      \
        _Pragma("unroll")                                                     \
        for (int q = 0; q < 16; ++q) {                                        \
            float4 ww = wq[q];                                                \
            _Pragma("unroll")                                                 \
            for (int e = 0; e < 4; ++e) {                                     \
                const int j2 = (q & 7)*4 + e;                                 \
                const int jj = j2 & 15;                                       \
                const int T = jj >> 3, r = (jj >> 1) & 3, col = jj & 1;       \
                const int par = col ? (((K)+1) & 1) : ((K) & 1);              \
                float val = (j2 < 16) ? c3c[par][T][r] : mxc[par][T][r];      \
                float wv_ = (e==0)?ww.x:(e==1)?ww.y:(e==2)?ww.z:ww.w;         \
                if (q < 8) { if (q & 1) pv0b = fmaf(wv_, val, pv0b);          \
                             else       pv0a = fmaf(wv_, val, pv0a); }        \
                else       { if (q & 1) pv1b = fmaf(wv_, val, pv1b);          \
                             else       pv1a = fmaf(wv_, val, pv1a); }        \
            }                                                                 \
        }                                                                     \
    }                                                                         \
    float pv0 = pv0a + pv0b, pv1 = pv1a + pv1b;                               \
    pv0 += __shfl_xor(pv0, 16); pv0 += __shfl_xor(pv0, 32);                   \
    pv1 += __shfl_xor(pv1, 16); pv1 += __shfl_xor(pv1, 32);                   \
    const float r0 = pv0 + bhp0, r1 = pv1 + bhp1;                             \
    if (lane < 16) {                                                          \
        float2 o; o.x = r0; o.y = r1;                                         \
        *(float2*)&out[(size_t)(st*BATCH + bped + lane)*2] = o;               \
    }                                                                         \
    if (st < SEQLEN-1) {                                                      \
        if (lane < 16) {                                                      \
            float2 o2; o2.x = r0; o2.y = r1;                                  \
            *(float2*)&pos_s[wv][st & 3][lane][0] = o2;   /* tau st+8 */      \
        }                                                                     \
        CONV1COL((st+2)&3, (st+3)&3, st&3, (K)%3);   /* col st+6 */           \
        CONV2COL(((K)+1)%3);                         /* col st+4 */           \
        CONV3COL(((K)+2)%3, (K)&1);                  /* col st+2 */           \
    }                                                                         \
} while(0)

__global__ __launch_bounds__(256, 1)
void enc_wp(const float* __restrict__ obs,
            const float* __restrict__ Wse, const float* __restrict__ bse,
            const float* __restrict__ v1, const float* __restrict__ g1, const float* __restrict__ b1,
            const float* __restrict__ v2, const float* __restrict__ g2, const float* __restrict__ b2,
            const float* __restrict__ v3, const float* __restrict__ g3, const float* __restrict__ b3,
            const float* __restrict__ Whp, const float* __restrict__ bhp,
            float* __restrict__ out)
{
    __shared__ __align__(16) ushort_t s1sh[4][16][72], s1sl[4][16][72];       // 18432 B
    __shared__ __align__(16) ushort_t s2sh[4][3][16][40], s2sl[4][3][16][40]; // 30720 B
    __shared__ __align__(16) float    pos_s[4][4][16][2];                     //  2048 B
    __shared__ __align__(16) float    whp_s[4][68];                           //  1088 B (padded stride)
    __shared__ __align__(16) ushort_t c3wh[6][64][8], c3wl[6][64][8];         // 12288 B (shared weights)
    __shared__ __align__(16) float    b2s[32], b3s[32];                       //   256 B
                                                                              // total 64832 B

    const int tid  = threadIdx.x;
    const int wv   = tid >> 6;
    const int lane = tid & 63;
    const int n    = lane & 15, kg = lane >> 4;
    const int bped = (blockIdx.x*4 + wv)*16;

    // prologue scratch overlaid on wave 0's s2 region (dead until warm-up conv2,
    // which is after sync2)
    float* scr   = (float*)&s2sh[0][0][0][0];
    float* wse_s = scr;          // 128
    float* bse_s = scr + 128;    // 64
    float* sc2_s = scr + 192;    // 32
    float* sc3_s = scr + 224;    // 32

    // ---- shared staging (wave 0) ----
    if (wv == 0) {
        wse_s[lane] = Wse[lane]; wse_s[64 + lane] = Wse[64 + lane];
        bse_s[lane] = bse[lane];
        if (lane < 32) {
            b2s[lane] = b2[lane];
            const float* v = v2 + lane*192; float s = 0.f;
            for (int j = 0; j < 192; ++j) s += v[j]*v[j];
            sc2_s[lane] = g2[lane] / sqrtf(s);
        } else {
            b3s[lane-32] = b3[lane-32];
            const float* v = v3 + (lane-32)*96; float s = 0.f;
            for (int j = 0; j < 96; ++j) s += v[j]*v[j];
            sc3_s[lane-32] = g3[lane-32] / sqrtf(s);
        }
        #pragma unroll
        for (int q = 0; q < 4; ++q) {   // Whp pre-permuted per kg-row
            int d = lane >> 5, jp = lane & 31, jj = jp & 15;
            int T = jj >> 3, r = (jj >> 1) & 3, col = jj & 1;
            int off = (T*16 + q*4 + r)*2 + col + ((jp >= 16) ? 64 : 0);
            whp_s[q][lane] = Whp[d*128 + off];
        }
    }
    __syncthreads();   // sync1: scratch + whp ready

    // ---- per-wave setup (reads scratch; no cross-wave writes except wv==1 c3w) ----
    float ccA0, ccA1, ccA2, ccB0, ccB1, ccB2, cK1;
    {
        const float* v = v1 + lane*192; float s = 0.f;
        for (int j = 0; j < 192; ++j) s += v[j]*v[j];
        const float sc1 = g1[lane] / sqrtf(s);
        float dA0=0,dA1=0,dA2=0,dB0=0,dB1=0,dB2=0,dC0=0,dC1=0,dC2=0;
        const float* vr = v1 + lane*192;
        #pragma unroll 4
        for (int ic = 0; ic < 64; ++ic) {
            float w0 = vr[ic*3], w1 = vr[ic*3+1], w2 = vr[ic*3+2];
            float we0 = wse_s[ic*2], we1 = wse_s[ic*2+1], be = bse_s[ic];
            dA0 = fmaf(w0, we0, dA0); dB0 = fmaf(w0, we1, dB0); dC0 = fmaf(w0, be, dC0);
            dA1 = fmaf(w1, we0, dA1); dB1 = fmaf(w1, we1, dB1); dC1 = fmaf(w1, be, dC1);
            dA2 = fmaf(w2, we0, dA2); dB2 = fmaf(w2, we1, dB2); dC2 = fmaf(w2, be, dC2);
        }
        ccA0 = sc1*dA0; ccA1 = sc1*dA1; ccA2 = sc1*dA2;
        ccB0 = sc1*dB0; ccB1 = sc1*dB1; ccB2 = sc1*dB2;
        cK1  = fmaf(sc1, (dC0 + dC1) + dC2, b1[lane]);
    }
    // conv2 weight fragments (registers, per wave)
    short8 c2h[2][6], c2l[2][6];
    #pragma unroll
    for (int T = 0; T < 2; ++T) {
        const int oc2 = T*16 + n;
        const float s2s = sc2_s[oc2];
        #pragma unroll
        for (int kb = 0; kb < 6; ++kb) {
            const int tap = kb >> 1, ich = kb & 1;
            #pragma unroll
            for (int j = 0; j < 8; ++j) {
                const int ic = ich*32 + kg*8 + j;
                float w = v2[(size_t)(oc2*64 + ic)*3 + tap] * s2s;
                ushort_t hb = f2bf(w);
                c2h[T][kb][j] = (short)hb;
                c2l[T][kb][j] = (short)f2bf(w - bf2f(hb));
            }
        }
    }
    // conv3 weight fragments -> shared LDS (one copy, filled by wave 1)
    if (wv == 1) {
        #pragma unroll
        for (int f = 0; f < 6; ++f) {
            const int T = f / 3, kb = f % 3;
            const int oc = T*16 + n;
            const float s3s = sc3_s[oc];
            #pragma unroll
            for (int j = 0; j < 8; ++j) {
                const int ic = kg*8 + j;
                float w = v3[(size_t)(oc*32 + ic)*3 + kb] * s3s;
                ushort_t hb = f2bf(w);
                c3wh[f][lane][j] = hb;
                c3wl[f][lane][j] = f2bf(w - bf2f(hb));
            }
        }
    }
    const float bhp0 = bhp[0], bhp1 = bhp[1];
    __syncthreads();   // sync2: last barrier — scratch consumed, c3w ready

    // ---- rotating per-wave state ----
    short8 s1fh[3][2], s1fl[3][2];
    f32x4 c3c[2][2], mxc[2][2];

    // ---- warm-up (s1 cols 0..5, conv2 0..3, conv3 0..1); all same-wave ----
    STAGE2(0); STAGE2(2);                 // taus 0..3
    CONV1COL(0, 1, 2, 0);                 // col0
    CONV1COL(1, 2, 3, 1);                 // col1
    STAGE2(4);                            // taus 4,5 -> slots 0,1
    CONV1COL(2, 3, 0, 2);                 // col2 (t2,3,4)
    CONV2COL(0);                          // conv2 col0
    CONV1COL(3, 0, 1, 0);                 // col3 (t3,4,5)
    CONV2COL(1);                          // conv2 col1
    STAGE2(6);                            // taus 6,7 -> slots 2,3
    CONV1COL(0, 1, 2, 1);                 // col4 (t4,5,6)
    CONV2COL(2);                          // conv2 col2
    CONV3COL(0, 0);                       // conv3 col0
    CONV1COL(1, 2, 3, 2);                 // col5 (t5,6,7)
    CONV2COL(0);                          // conv2 col3
    CONV3COL(1, 1);                       // conv3 col1

    // ---- 12 recurrent steps, zero barriers ----
    #pragma unroll 1
    for (int hh = 0; hh < 2; ++hh) {
        const int sbase = hh * 6;
        STEP(0); STEP(1); STEP(2); STEP(3); STEP(4); STEP(5);
    }
}

extern "C" void kernel_launch(void* const* d_in, const int* in_sizes, int n_in,
                              void* d_out, int out_size, void* d_ws, size_t ws_size,
                              hipStream_t stream)
{
    const float* obs = (const float*)d_in[0];
    // d_in[1] last_pos, d_in[2] last_pos_rel: dead state (never reaches output)
    const float* Wse = (const float*)d_in[3];
    const float* bse = (const float*)d_in[4];
    const float* v1  = (const float*)d_in[5];
    const float* g1  = (const float*)d_in[6];
    const float* b1  = (const float*)d_in[7];
    const float* v2  = (const float*)d_in[8];
    const float* g2  = (const float*)d_in[9];
    const float* b2  = (const float*)d_in[10];
    const float* v3  = (const float*)d_in[11];
    const float* g3  = (const float*)d_in[12];
    const float* b3  = (const float*)d_in[13];
    const float* Whp = (const float*)d_in[14];
    const float* bhp = (const float*)d_in[15];
    // d_in[16] seq_start_end: structurally seg = ped>>3 ; d_in[17] seq_len = 12

    enc_wp<<<NBLK, 256, 0, stream>>>(obs, Wse, bse, v1, g1, b1, v2, g2, b2,
                                     v3, g3, b3, Whp, bhp, (float*)d_out);
}

// Round 6
// 175.248 us; speedup vs baseline: 1.1975x; 1.1807x over previous
//
#include <hip/hip_runtime.h>

#define BATCH 32768
#define SEQLEN 12
#define NBLK 512   // 256 threads = 4 waves; each wave privately owns 16 peds (2 scenes)

typedef short short8 __attribute__((ext_vector_type(8)));
typedef float f32x4 __attribute__((ext_vector_type(4)));
typedef unsigned short ushort_t;

static __device__ __forceinline__ unsigned short f2bf(float x) {
    unsigned u = __float_as_uint(x);
    return (unsigned short)((u + 0x7FFFu + ((u >> 16) & 1u)) >> 16);  // RNE
}
static __device__ __forceinline__ float bf2f(unsigned short h) {
    return __uint_as_float(((unsigned)h) << 16);
}

#define MFMA __builtin_amdgcn_mfma_f32_16x16x32_bf16

// Wave-private v3. r5 post-mortem: VGPR 216 + ~64 AGPR > 256 combined ->
// 1 wave/SIMD, 2 rounds, 135 us. Diet: conv2 weights (96 regs) -> shared LDS;
// conv3 hi in LDS / lo in regs (+24); s2 LDS ring (30.7KB) -> 1-col stage +
// reg frags (+24). Net ~210 combined, LDS 62784 <= 64KB static cap.
// launch_bounds(256,2) enforces <=256 combined -> 2 waves/SIMD; 2 blocks/CU
// by LDS -> 512 blocks in ONE round with SIMD-level latency overlap.

// ---- conv1: one ped column element (exact fp32, same op order as verified) ----
#define C1PED(PX, PY, QX, QY, RX, RY, PPED) do {                              \
    float v_ = cK1;                                                           \
    v_ = fmaf(ccA0, PX, v_); v_ = fmaf(ccB0, PY, v_);                         \
    v_ = fmaf(ccA1, QX, v_); v_ = fmaf(ccB1, QY, v_);                         \
    v_ = fmaf(ccA2, RX, v_); v_ = fmaf(ccB2, RY, v_);                         \
    v_ = fmaxf(v_, 0.f);                                                      \
    ushort_t h_ = f2bf(v_);                                                   \
    s1sh[wv][PPED][lane] = h_;                                                \
    s1sl[wv][PPED][lane] = f2bf(v_ - bf2f(h_));                               \
} while(0)

#define S1_FRAGREAD(SL) do {                                                  \
    s1fh[SL][0] = *(const short8*)&s1sh[wv][n][kg*8];                         \
    s1fh[SL][1] = *(const short8*)&s1sh[wv][n][32 + kg*8];                    \
    s1fl[SL][0] = *(const short8*)&s1sl[wv][n][kg*8];                         \
    s1fl[SL][1] = *(const short8*)&s1sl[wv][n][32 + kg*8];                    \
} while(0)

// conv1 column from pos ring slots SA,SB,SC -> s1 staging -> reg frag slot SL
#define CONV1COL(SA, SB, SC, SL) do {                                         \
    _Pragma("unroll")                                                         \
    for (int pp_ = 0; pp_ < 8; ++pp_) {                                       \
        float4 fa_ = *(const float4*)&pos_s[wv][SA][2*pp_][0];                \
        float4 fb_ = *(const float4*)&pos_s[wv][SB][2*pp_][0];                \
        float4 fc_ = *(const float4*)&pos_s[wv][SC][2*pp_][0];                \
        C1PED(fa_.x, fa_.y, fb_.x, fb_.y, fc_.x, fc_.y, 2*pp_);               \
        C1PED(fa_.z, fa_.w, fb_.z, fb_.w, fc_.z, fc_.w, 2*pp_+1);             \
    }                                                                         \
    S1_FRAGREAD(SL);                                                          \
} while(0)

// conv2 column c (c%3 == CM3): s1 reg frags x LDS weights -> s2 1-col stage
// -> reg frag slot CM3
#define CONV2COL(CM3) do {                                                    \
    _Pragma("unroll")                                                         \
    for (int T = 0; T < 2; ++T) {                                             \
        f32x4 a1 = {0.f,0.f,0.f,0.f}, a2 = {0.f,0.f,0.f,0.f},                 \
              a3 = {0.f,0.f,0.f,0.f};                                         \
        _Pragma("unroll")                                                     \
        for (int kb = 0; kb < 6; ++kb) {                                      \
            const int sl = ((CM3) + (kb >> 1)) % 3, ich = kb & 1;             \
            const short8 wh = *(const short8*)&c2wh[T*6+kb][lane][0];         \
            const short8 wl = *(const short8*)&c2wl[T*6+kb][lane][0];         \
            a1 = MFMA(wh, s1fh[sl][ich], a1, 0, 0, 0);                        \
            a2 = MFMA(wh, s1fl[sl][ich], a2, 0, 0, 0);                        \
            a3 = MFMA(wl, s1fh[sl][ich], a3, 0, 0, 0);                        \
        }                                                                     \
        const float4 bb = *(const float4*)&b2s[T*16 + kg*4];                  \
        float w0 = fmaxf(a1[0]+a2[0]+a3[0]+bb.x, 0.f);                        \
        float w1 = fmaxf(a1[1]+a2[1]+a3[1]+bb.y, 0.f);                        \
        float w2 = fmaxf(a1[2]+a2[2]+a3[2]+bb.z, 0.f);                        \
        float w3 = fmaxf(a1[3]+a2[3]+a3[3]+bb.w, 0.f);                        \
        ushort_t h0=f2bf(w0), h1=f2bf(w1), h2=f2bf(w2), h3=f2bf(w3);          \
        *(uint2*)&s2sh[wv][n][T*16 + kg*4] = make_uint2(                      \
            (unsigned)h0 | ((unsigned)h1 << 16),                              \
            (unsigned)h2 | ((unsigned)h3 << 16));                             \
        *(uint2*)&s2sl[wv][n][T*16 + kg*4] = make_uint2(                      \
            (unsigned)f2bf(w0-bf2f(h0)) | ((unsigned)f2bf(w1-bf2f(h1)) << 16),\
            (unsigned)f2bf(w2-bf2f(h2)) | ((unsigned)f2bf(w3-bf2f(h3)) << 16));\
    }                                                                         \
    s2fh[(CM3)] = *(const short8*)&s2sh[wv][n][kg*8];                         \
    s2fl[(CM3)] = *(const short8*)&s2sl[wv][n][kg*8];                         \
} while(0)

// conv3 column v (v%3 == VM3, v&1 == PARI): s2 reg frags; hi weights LDS,
// lo weights regs. Outputs + scene-max stay in regs.
#define CONV3COL(VM3, PARI) do {                                              \
    _Pragma("unroll")                                                         \
    for (int T = 0; T < 2; ++T) {                                             \
        f32x4 a1 = {0.f,0.f,0.f,0.f}, a2 = {0.f,0.f,0.f,0.f},                 \
              a3 = {0.f,0.f,0.f,0.f};                                         \
        _Pragma("unroll")                                                     \
        for (int kb = 0; kb < 3; ++kb) {                                      \
            const int sl = ((VM3) + kb) % 3;                                  \
            const short8 wh = *(const short8*)&c3wh[T*3+kb][lane][0];         \
            a1 = MFMA(wh, s2fh[sl], a1, 0, 0, 0);                             \
            a2 = MFMA(wh, s2fl[sl], a2, 0, 0, 0);                             \
            a3 = MFMA(c3l[T][kb], s2fh[sl], a3, 0, 0, 0);                     \
        }                                                                     \
        const float4 b3v = *(const float4*)&b3s[T*16 + kg*4];                 \
        float m0 = fmaxf(a1[0]+a2[0]+a3[0]+b3v.x, 0.f);                       \
        float m1 = fmaxf(a1[1]+a2[1]+a3[1]+b3v.y, 0.f);                       \
        float m2 = fmaxf(a1[2]+a2[2]+a3[2]+b3v.z, 0.f);                       \
        float m3 = fmaxf(a1[3]+a2[3]+a3[3]+b3v.w, 0.f);                       \
        c3c[PARI][T] = (f32x4){m0, m1, m2, m3};                               \
        _Pragma("unroll")                                                     \
        for (int msk = 1; msk <= 4; msk <<= 1) {                              \
            m0 = fmaxf(m0, __shfl_xor(m0, msk));                              \
            m1 = fmaxf(m1, __shfl_xor(m1, msk));                              \
            m2 = fmaxf(m2, __shfl_xor(m2, msk));                              \
            m3 = fmaxf(m3, __shfl_xor(m3, msk));                              \
        }                                                                     \
        mxc[PARI][T] = (f32x4){m0, m1, m2, m3};                               \
    }                                                                         \
} while(0)

// stage obs taus T0,T0+1 into pos ring (slot = tau&3)
#define STAGE2(T0) do {                                                       \
    const int tau_ = (T0) + (lane >> 5);                                      \
    const int p_ = (lane >> 1) & 15, c_ = lane & 1;                           \
    pos_s[wv][tau_ & 3][p_][c_] =                                             \
        obs[(size_t)(tau_*BATCH + bped + p_)*2 + c_];                         \
} while(0)

// one recurrent step: h2p(st) -> conv1(st+6) -> conv2(st+4) -> conv3(st+2)
#define STEP(K) do {                                                          \
    const int st = sbase + (K);                                               \
    float pv0a = 0.f, pv0b = 0.f, pv1a = 0.f, pv1b = 0.f;                     \
    {                                                                         \
        const float4* wq = (const float4*)&whp_s[kg][0];                      \
        _Pragma("unroll")                                                     \
        for (int q = 0; q < 16; ++q) {                                        \
            float4 ww = wq[q];                                                \
            _Pragma("unroll")                                                 \
            for (int e = 0; e < 4; ++e) {                                     \
                const int j2 = (q & 7)*4 + e;                                 \
                const int jj = j2 & 15;                                       \
                const int T = jj >> 3, r = (jj >> 1) & 3, col = jj & 1;       \
                const int par = col ? (((K)+1) & 1) : ((K) & 1);              \
                float val = (j2 < 16) ? c3c[par][T][r] : mxc[par][T][r];      \
                float wv_ = (e==0)?ww.x:(e==1)?ww.y:(e==2)?ww.z:ww.w;         \
                if (q < 8) { if (q & 1) pv0b = fmaf(wv_, val, pv0b);          \
                             else       pv0a = fmaf(wv_, val, pv0a); }        \
                else       { if (q & 1) pv1b = fmaf(wv_, val, pv1b);          \
                             else       pv1a = fmaf(wv_, val, pv1a); }        \
            }                                                                 \
        }                                                                     \
    }                                                                         \
    float pv0 = pv0a + pv0b, pv1 = pv1a + pv1b;                               \
    pv0 += __shfl_xor(pv0, 16); pv0 += __shfl_xor(pv0, 32);                   \
    pv1 += __shfl_xor(pv1, 16); pv1 += __shfl_xor(pv1, 32);                   \
    const float r0 = pv0 + bhp0, r1 = pv1 + bhp1;                             \
    if (lane < 16) {                                                          \
        float2 o; o.x = r0; o.y = r1;                                         \
        *(float2*)&out[(size_t)(st*BATCH + bped + lane)*2] = o;               \
    }                                                                         \
    if (st < SEQLEN-1) {                                                      \
        if (lane < 16) {                                                      \
            float2 o2; o2.x = r0; o2.y = r1;                                  \
            *(float2*)&pos_s[wv][st & 3][lane][0] = o2;   /* tau st+8 */      \
        }                                                                     \
        CONV1COL((st+2)&3, (st+3)&3, st&3, (K)%3);   /* col st+6 */           \
        CONV2COL(((K)+1)%3);                         /* col st+4 */           \
        CONV3COL(((K)+2)%3, (K)&1);                  /* col st+2 */           \
    }                                                                         \
} while(0)

__global__ __launch_bounds__(256, 2)
void enc_wp(const float* __restrict__ obs,
            const float* __restrict__ Wse, const float* __restrict__ bse,
            const float* __restrict__ v1, const float* __restrict__ g1, const float* __restrict__ b1,
            const float* __restrict__ v2, const float* __restrict__ g2, const float* __restrict__ b2,
            const float* __restrict__ v3, const float* __restrict__ g3, const float* __restrict__ b3,
            const float* __restrict__ Whp, const float* __restrict__ bhp,
            float* __restrict__ out)
{
    __shared__ __align__(16) ushort_t s1sh[4][16][72], s1sl[4][16][72];  // 18432 B
    __shared__ __align__(16) ushort_t s2sh[4][16][40], s2sl[4][16][40];  // 10240 B
    __shared__ __align__(16) float    pos_s[4][4][16][2];                //  2048 B
    __shared__ __align__(16) float    whp_s[4][68];                      //  1088 B (padded)
    __shared__ __align__(16) ushort_t c2wh[12][64][8], c2wl[12][64][8];  // 24576 B (shared)
    __shared__ __align__(16) ushort_t c3wh[6][64][8];                    //  6144 B (shared, hi)
    __shared__ __align__(16) float    b2s[32], b3s[32];                  //   256 B
                                                                         // total 62784 B

    const int tid  = threadIdx.x;
    const int wv   = tid >> 6;
    const int lane = tid & 63;
    const int n    = lane & 15, kg = lane >> 4;
    const int bped = (blockIdx.x*4 + wv)*16;

    // prologue scratch overlaid on s1 region (s1 first written in warm-up,
    // i.e. after sync2 when scratch is fully consumed)
    float* scr   = (float*)&s1sh[0][0][0];
    float* wse_s = scr;          // 128
    float* bse_s = scr + 128;    // 64
    float* sc2_s = scr + 192;    // 32
    float* sc3_s = scr + 224;    // 32

    // ---- shared staging (wave 0) ----
    if (wv == 0) {
        wse_s[lane] = Wse[lane]; wse_s[64 + lane] = Wse[64 + lane];
        bse_s[lane] = bse[lane];
        if (lane < 32) {
            b2s[lane] = b2[lane];
            const float* v = v2 + lane*192; float s = 0.f;
            for (int j = 0; j < 192; ++j) s += v[j]*v[j];
            sc2_s[lane] = g2[lane] / sqrtf(s);
        } else {
            b3s[lane-32] = b3[lane-32];
            const float* v = v3 + (lane-32)*96; float s = 0.f;
            for (int j = 0; j < 96; ++j) s += v[j]*v[j];
            sc3_s[lane-32] = g3[lane-32] / sqrtf(s);
        }
        #pragma unroll
        for (int q = 0; q < 4; ++q) {   // Whp pre-permuted per kg-row
            int d = lane >> 5, jp = lane & 31, jj = jp & 15;
            int T = jj >> 3, r = (jj >> 1) & 3, col = jj & 1;
            int off = (T*16 + q*4 + r)*2 + col + ((jp >= 16) ? 64 : 0);
            whp_s[q][lane] = Whp[d*128 + off];
        }
    }
    __syncthreads();   // sync1: scratch + whp + biases ready

    // ---- shared weight fills (waves 0,1) ----
    if (wv == 0) {          // conv2 weights hi/lo -> LDS
        #pragma unroll
        for (int f = 0; f < 12; ++f) {
            const int T = f / 6, kb = f % 6;
            const int oc = T*16 + n, tap = kb >> 1, ich = kb & 1;
            const float s2s = sc2_s[oc];
            #pragma unroll
            for (int j = 0; j < 8; ++j) {
                const int ic = ich*32 + kg*8 + j;
                float w = v2[(size_t)(oc*64 + ic)*3 + tap] * s2s;
                ushort_t hb = f2bf(w);
                c2wh[f][lane][j] = hb;
                c2wl[f][lane][j] = f2bf(w - bf2f(hb));
            }
        }
    } else if (wv == 1) {   // conv3 hi weights -> LDS
        #pragma unroll
        for (int f = 0; f < 6; ++f) {
            const int T = f / 3, kb = f % 3;
            const int oc = T*16 + n;
            const float s3s = sc3_s[oc];
            #pragma unroll
            for (int j = 0; j < 8; ++j) {
                const int ic = kg*8 + j;
                c3wh[f][lane][j] = f2bf(v3[(size_t)(oc*32 + ic)*3 + kb] * s3s);
            }
        }
    }

    // ---- per-wave setup ----
    float ccA0, ccA1, ccA2, ccB0, ccB1, ccB2, cK1;
    {
        const float* v = v1 + lane*192; float s = 0.f;
        for (int j = 0; j < 192; ++j) s += v[j]*v[j];
        const float sc1 = g1[lane] / sqrtf(s);
        float dA0=0,dA1=0,dA2=0,dB0=0,dB1=0,dB2=0,dC0=0,dC1=0,dC2=0;
        const float* vr = v1 + lane*192;
        #pragma unroll 4
        for (int ic = 0; ic < 64; ++ic) {
            float w0 = vr[ic*3], w1 = vr[ic*3+1], w2 = vr[ic*3+2];
            float we0 = wse_s[ic*2], we1 = wse_s[ic*2+1], be = bse_s[ic];
            dA0 = fmaf(w0, we0, dA0); dB0 = fmaf(w0, we1, dB0); dC0 = fmaf(w0, be, dC0);
            dA1 = fmaf(w1, we0, dA1); dB1 = fmaf(w1, we1, dB1); dC1 = fmaf(w1, be, dC1);
            dA2 = fmaf(w2, we0, dA2); dB2 = fmaf(w2, we1, dB2); dC2 = fmaf(w2, be, dC2);
        }
        ccA0 = sc1*dA0; ccA1 = sc1*dA1; ccA2 = sc1*dA2;
        ccB0 = sc1*dB0; ccB1 = sc1*dB1; ccB2 = sc1*dB2;
        cK1  = fmaf(sc1, (dC0 + dC1) + dC2, b1[lane]);
    }
    // conv3 LO weight fragments (per-wave registers; exact same values as before)
    short8 c3l[2][3];
    #pragma unroll
    for (int T = 0; T < 2; ++T) {
        const int oc = T*16 + n;
        const float s3s = sc3_s[oc];
        #pragma unroll
        for (int kb = 0; kb < 3; ++kb) {
            #pragma unroll
            for (int j = 0; j < 8; ++j) {
                const int ic = kg*8 + j;
                float w = v3[(size_t)(oc*32 + ic)*3 + kb] * s3s;
                c3l[T][kb][j] = (short)f2bf(w - bf2f(f2bf(w)));
            }
        }
    }
    const float bhp0 = bhp[0], bhp1 = bhp[1];
    __syncthreads();   // sync2: last barrier — scratch consumed, weights ready

    // ---- rotating per-wave state ----
    short8 s1fh[3][2], s1fl[3][2], s2fh[3], s2fl[3];
    f32x4 c3c[2][2], mxc[2][2];

    // ---- warm-up (s1 cols 0..5, conv2 0..3, conv3 0..1); all same-wave ----
    STAGE2(0); STAGE2(2);                 // taus 0..3
    CONV1COL(0, 1, 2, 0);                 // col0
    CONV1COL(1, 2, 3, 1);                 // col1
    STAGE2(4);                            // taus 4,5 -> slots 0,1
    CONV1COL(2, 3, 0, 2);                 // col2 (t2,3,4)
    CONV2COL(0);                          // conv2 col0
    CONV1COL(3, 0, 1, 0);                 // col3 (t3,4,5)
    CONV2COL(1);                          // conv2 col1
    STAGE2(6);                            // taus 6,7 -> slots 2,3
    CONV1COL(0, 1, 2, 1);                 // col4 (t4,5,6)
    CONV2COL(2);                          // conv2 col2
    CONV3COL(0, 0);                       // conv3 col0
    CONV1COL(1, 2, 3, 2);                 // col5 (t5,6,7)
    CONV2COL(0);                          // conv2 col3
    CONV3COL(1, 1);                       // conv3 col1

    // ---- 12 recurrent steps, zero barriers ----
    #pragma unroll 1
    for (int hh = 0; hh < 2; ++hh) {
        const int sbase = hh * 6;
        STEP(0); STEP(1); STEP(2); STEP(3); STEP(4); STEP(5);
    }
}

extern "C" void kernel_launch(void* const* d_in, const int* in_sizes, int n_in,
                              void* d_out, int out_size, void* d_ws, size_t ws_size,
                              hipStream_t stream)
{
    const float* obs = (const float*)d_in[0];
    // d_in[1] last_pos, d_in[2] last_pos_rel: dead state (never reaches output)
    const float* Wse = (const float*)d_in[3];
    const float* bse = (const float*)d_in[4];
    const float* v1  = (const float*)d_in[5];
    const float* g1  = (const float*)d_in[6];
    const float* b1  = (const float*)d_in[7];
    const float* v2  = (const float*)d_in[8];
    const float* g2  = (const float*)d_in[9];
    const float* b2  = (const float*)d_in[10];
    const float* v3  = (const float*)d_in[11];
    const float* g3  = (const float*)d_in[12];
    const float* b3  = (const float*)d_in[13];
    const float* Whp = (const float*)d_in[14];
    const float* bhp = (const float*)d_in[15];
    // d_in[16] seq_start_end: structurally seg = ped>>3 ; d_in[17] seq_len = 12

    enc_wp<<<NBLK, 256, 0, stream>>>(obs, Wse, bse, v1, g1, b1, v2, g2, b2,
                                     v3, g3, b3, Whp, bhp, (float*)d_out);
}